// Round 3
// baseline (877.821 us; speedup 1.0000x reference)
//
#include <hip/hip_runtime.h>
#include <math.h>

// Problem constants (from reference)
constexpr int R  = 5;
constexpr int E  = 50000;   // divisible by 4 (pass1 relies on this)
constexpr int NU = 20000;
constexpr int NI = 20000;
constexpr int NF = 4;
constexpr int DN = 16;
constexpr int DR = 64;
constexpr int DO = 64;
constexpr float TAU = 0.5f;
constexpr float INV_TAU = 2.0f;

// ---------------- Pass 1: 4 edges per wave (16 lanes per edge) ----------------
// lane = e*16 + f*4 + j  (e: edge-in-wave, f: factor, j: sub)
__global__ __launch_bounds__(256) void pass1_kernel(
    const float* __restrict__ user_h,      // (NF,R,NU,DN)
    const float* __restrict__ item_h,      // (NF,R,NI,DN)
    const float* __restrict__ user_hsum,   // (R,NU,NF,DN)
    const float* __restrict__ item_hsum,   // (R,NI,NF,DN)
    const float* __restrict__ review_feat, // (R,E,NF,DR)
    const float* __restrict__ prototypes,  // (NF,DR)
    const float* __restrict__ eta,         // (R,E)
    const int*   __restrict__ edge_src,    // (R,E)
    const int*   __restrict__ edge_dst,    // (R,E)
    const int*   __restrict__ kptr,
    float* __restrict__ blended_out,       // (R*E)
    float* __restrict__ norm_user,         // (NU)
    float* __restrict__ norm_item)         // (NI)
{
    const int lane = threadIdx.x & 63;
    const int w    = threadIdx.x >> 6;
    const int r    = blockIdx.y;
    const int base = (blockIdx.x * 4 + w) * 4;      // edge index within relation
    const int k    = *kptr;

    const int e  = lane >> 4;       // 0..3
    const int le = lane & 15;       // 0..15
    const int f  = le >> 2;         // 0..3
    const int j  = le & 3;          // 0..3

    const int ee = base + e;                        // < E always (E % 4 == 0)
    const long long re = (long long)r * E + ee;

    const int src = edge_src[re];
    const int dst = edge_dst[re];

    // ---- sim_k (l2norm dot over DN=16): quad f==0 only, float4 per lane ----
    float na = 0.f, nb = 0.f, ab = 0.f;
    if (f == 0) {
        const float4 ua = *(const float4*)(user_h + (((long long)k * R + r) * NU + src) * DN + j * 4);
        const float4 ia = *(const float4*)(item_h + (((long long)k * R + r) * NI + dst) * DN + j * 4);
        na = ua.x*ua.x + ua.y*ua.y + ua.z*ua.z + ua.w*ua.w;
        nb = ia.x*ia.x + ia.y*ia.y + ia.z*ia.z + ia.w*ia.w;
        ab = ua.x*ia.x + ua.y*ia.y + ua.z*ia.z + ua.w*ia.w;
    }
    na += __shfl_xor(na, 1, 64); na += __shfl_xor(na, 2, 64);
    nb += __shfl_xor(nb, 1, 64); nb += __shfl_xor(nb, 2, 64);
    ab += __shfl_xor(ab, 1, 64); ab += __shfl_xor(ab, 2, 64);

    // ---- sim_all over hsum rows: lane (f,j) takes floats [f*16 + j*4 ..] ----
    const float4 rs = *(const float4*)(user_hsum + ((long long)r * NU + src) * (NF * DN) + le * 4);
    const float4 cs = *(const float4*)(item_hsum + ((long long)r * NI + dst) * (NF * DN) + le * 4);
    float p = rs.x*cs.x + rs.y*cs.y + rs.z*cs.z + rs.w*cs.w;
    p += __shfl_xor(p, 1, 64); p += __shfl_xor(p, 2, 64);   // sum over j -> sim_all[f]
    float denom_sim = __expf(p * INV_TAU);
    denom_sim += __shfl_xor(denom_sim, 4, 64);
    denom_sim += __shfl_xor(denom_sim, 8, 64);              // sum over f

    // ---- anchors: lane (f,j) reads 4 chunks of rf row (full 64B lines/instr) ----
    const float4* rf4 = (const float4*)review_feat + re * (NF * DR / 4);
    const float4* pr4 = (const float4*)prototypes;
    float q = 0.f;
#pragma unroll
    for (int c = 0; c < 4; ++c) {
        const float4 a = rf4[f * 16 + c * 4 + j];
        const float4 b = pr4[f * 16 + c * 4 + j];
        q += a.x*b.x + a.y*b.y + a.z*b.z + a.w*b.w;
    }
    q += __shfl_xor(q, 1, 64); q += __shfl_xor(q, 2, 64);   // sum over j -> anchor_all[f]
    float ea = __expf(q * INV_TAU);
    float denom_anc = ea;
    denom_anc += __shfl_xor(denom_anc, 4, 64);
    denom_anc += __shfl_xor(denom_anc, 8, 64);              // sum over f
    const float ea_k = __shfl(ea, (lane & 48) | (k << 2), 64);

    if (le == 0) {
        const float sim_k = ab / (fmaxf(sqrtf(na), 1e-12f) * fmaxf(sqrtf(nb), 1e-12f)) * INV_TAU;
        const float exp_anchor = ea_k / denom_anc;
        const float exp_sim    = __expf(sim_k) / denom_sim;
        const float g = 1.0f / (1.0f + __expf(-eta[re]));
        const float blended = g * exp_anchor + (1.0f - g) * exp_sim;
        blended_out[re] = blended;
        atomicAdd(&norm_user[src], blended);
        atomicAdd(&norm_item[dst], blended);
    }
}

// ---------------- Kernel A: dense node transform ----------------
__global__ __launch_bounds__(256) void nodexf_kernel(
    const float* __restrict__ user_h,
    const float* __restrict__ item_h,
    const float* __restrict__ node_w_fwd,   // (R,DN,DN)
    const float* __restrict__ node_w_rev,   // (R,DN,DN)
    const int*   __restrict__ kptr,
    float* __restrict__ hu_t,               // (R,NU,DN)
    float* __restrict__ hi_t)               // (R,NI,DN)
{
    const int r    = blockIdx.y;
    const int side = blockIdx.z;
    const int n0   = blockIdx.x * 64;
    const int k    = *kptr;
    const int N    = side ? NI : NU;
    const float* h    = side ? item_h : user_h;
    const float* wsrc = side ? node_w_rev : node_w_fwd;
    float* out        = side ? hi_t : hu_t;

    __shared__ __align__(16) float lds_h[64 * 16];
    __shared__ float lds_w[16 * 17];

    const int t = threadIdx.x;
    {
        const int o = t >> 4, d = t & 15;
        lds_w[o * 17 + d] = wsrc[((long long)r * DN + o) * DN + d];
    }
    {
        const int row = t >> 2, c = t & 3;
        if (n0 + row < N) {
            const float4 v = *(const float4*)(h + (((long long)k * R + r) * N + n0 + row) * DN + c * 4);
            *(float4*)&lds_h[t * 4] = v;
        }
    }
    __syncthreads();

    const int o = t & 15;
#pragma unroll
    for (int p = 0; p < 4; ++p) {
        const int nl = p * 16 + (t >> 4);
        const int n = n0 + nl;
        if (n < N) {
            float acc = 0.f;
#pragma unroll
            for (int d = 0; d < DN; ++d)
                acc += lds_h[nl * 16 + d] * lds_w[o * 17 + d];
            out[((long long)r * N + n) * DN + o] = acc;
        }
    }
}

// ---------------- Pass 2b: lane-per-edge, wave covers 4 outputs ----------------
// Block: 256 thr = 4 waves; tile = 64 edges. Wave w handles o = w*4..w*4+3.
// rf rows per-lane from LDS (stride-68, conflict-free); weights via wave-uniform
// LDS broadcast reads.
__global__ __launch_bounds__(256) void pass2b_kernel(
    const float* __restrict__ hu_t,
    const float* __restrict__ hi_t,
    const float* __restrict__ review_feat,
    const float* __restrict__ review_w_fwd,  // (R,DN,DR)
    const float* __restrict__ review_w_rev,  // (R,DN,DR)
    const int*   __restrict__ edge_src,
    const int*   __restrict__ edge_dst,
    const int*   __restrict__ kptr,
    const float* __restrict__ blended,
    const float* __restrict__ norm_user,
    const float* __restrict__ norm_item,
    float* __restrict__ user_msg,  // (NU,DN)
    float* __restrict__ item_msg,  // (NI,DN)
    float* __restrict__ int_dist)  // (R*E)
{
    constexpr int EPB = 64;
    constexpr int RSTRIDE = 68;        // words; 16B-aligned, uniform bank spread
    const int r    = blockIdx.y;
    const int e0   = blockIdx.x * EPB;
    const int k    = *kptr;
    const int t    = threadIdx.x;
    const int lane = t & 63;
    const int w    = t >> 6;

    __shared__ __align__(16) float wf[DN * DR];
    __shared__ __align__(16) float wr[DN * DR];
    __shared__ __align__(16) float rf[EPB * RSTRIDE];

    // stage weights: 1024 floats each, one float4 per thread, coalesced
    {
        const int i = t * 4;
        *(float4*)&wf[i] = *(const float4*)(review_w_fwd + (long long)r * (DN * DR) + i);
        *(float4*)&wr[i] = *(const float4*)(review_w_rev + (long long)r * (DN * DR) + i);
    }
    // stage rf tile: 64 rows x 64 floats; thread t: row t>>2, 64B chunk (t&3)
    {
        const int row = t >> 2;
        const int c0  = (t & 3) * 16;
        const int ee  = e0 + row;
        if (ee < E) {
            const float4* s = (const float4*)(review_feat +
                (((long long)r * E + ee) * NF + k) * DR + c0);
            float4* d = (float4*)&rf[row * RSTRIDE + c0];
            d[0] = s[0]; d[1] = s[1]; d[2] = s[2]; d[3] = s[3];
        }
    }
    __syncthreads();

    const int ee = e0 + lane;
    const int ob = w * 4;
    float accf[4] = {0.f, 0.f, 0.f, 0.f};
    float accr[4] = {0.f, 0.f, 0.f, 0.f};

    const float* rfrow = &rf[lane * RSTRIDE];
#pragma unroll 4
    for (int c = 0; c < 16; ++c) {
        const float4 a = *(const float4*)&rfrow[c * 4];          // per-lane b128
#pragma unroll
        for (int jj = 0; jj < 4; ++jj) {
            const float4 bf = *(const float4*)&wf[(ob + jj) * DR + c * 4];  // uniform
            const float4 br = *(const float4*)&wr[(ob + jj) * DR + c * 4];  // uniform
            accf[jj] += a.x*bf.x + a.y*bf.y + a.z*bf.z + a.w*bf.w;
            accr[jj] += a.x*br.x + a.y*br.y + a.z*br.z + a.w*br.w;
        }
    }

    if (ee < E) {
        const long long re = (long long)r * E + ee;
        const int src = edge_src[re];
        const int dst = edge_dst[re];
        const float wgt = blended[re] * rsqrtf(norm_user[src] * norm_item[dst]);
        if (w == 0) int_dist[re] = wgt;
        const float4 hu = *(const float4*)(hu_t + ((long long)r * NU + src) * DN + ob);
        const float4 hi = *(const float4*)(hi_t + ((long long)r * NI + dst) * DN + ob);
        atomicAdd(&item_msg[(long long)dst * DN + ob + 0], (accf[0] + hu.x) * wgt);
        atomicAdd(&item_msg[(long long)dst * DN + ob + 1], (accf[1] + hu.y) * wgt);
        atomicAdd(&item_msg[(long long)dst * DN + ob + 2], (accf[2] + hu.z) * wgt);
        atomicAdd(&item_msg[(long long)dst * DN + ob + 3], (accf[3] + hu.w) * wgt);
        atomicAdd(&user_msg[(long long)src * DN + ob + 0], (accr[0] + hi.x) * wgt);
        atomicAdd(&user_msg[(long long)src * DN + ob + 1], (accr[1] + hi.y) * wgt);
        atomicAdd(&user_msg[(long long)src * DN + ob + 2], (accr[2] + hi.z) * wgt);
        atomicAdd(&user_msg[(long long)src * DN + ob + 3], (accr[3] + hi.w) * wgt);
    }
}

// ---------------- Pass 3: one thread per (node, j) ----------------
__global__ __launch_bounds__(256) void pass3_kernel(
    const float* __restrict__ user_msg,
    const float* __restrict__ item_msg,
    const float* __restrict__ ufc_w,  // (DO,DN)
    const float* __restrict__ ufc_b,  // (DO)
    const float* __restrict__ ifc_w,
    const float* __restrict__ ifc_b,
    float* __restrict__ ufeat,        // (NU,DO)
    float* __restrict__ ifeat)        // (NI,DO)
{
    const long long t = (long long)blockIdx.x * blockDim.x + threadIdx.x;
    const long long nu_total = (long long)NU * DO;
    const long long total = nu_total + (long long)NI * DO;
    if (t >= total) return;
    const bool is_item = (t >= nu_total);
    const long long tt = is_item ? (t - nu_total) : t;
    const int j = (int)(tt & 63);
    const long long n = tt >> 6;

    const float* msg  = (is_item ? item_msg : user_msg) + n * DN;
    const float* wrow = (is_item ? ifc_w : ufc_w) + (long long)j * DN;
    float acc = (is_item ? ifc_b : ufc_b)[j];
#pragma unroll
    for (int d = 0; d < DN; ++d) {
        float x = msg[d];
        x = (x > 0.f) ? x : 0.1f * x;
        acc += x * wrow[d];
    }
    (is_item ? ifeat : ufeat)[tt] = acc;
}

extern "C" void kernel_launch(void* const* d_in, const int* in_sizes, int n_in,
                              void* d_out, int out_size, void* d_ws, size_t ws_size,
                              hipStream_t stream) {
    const float* user_h       = (const float*)d_in[0];
    const float* item_h       = (const float*)d_in[1];
    const float* user_hsum    = (const float*)d_in[2];
    const float* item_hsum    = (const float*)d_in[3];
    const float* review_feat  = (const float*)d_in[4];
    const float* prototypes   = (const float*)d_in[5];
    const float* eta          = (const float*)d_in[6];
    const float* node_w_fwd   = (const float*)d_in[7];
    const float* review_w_fwd = (const float*)d_in[8];
    const float* node_w_rev   = (const float*)d_in[9];
    const float* review_w_rev = (const float*)d_in[10];
    const float* ufc_w        = (const float*)d_in[11];
    const float* ufc_b        = (const float*)d_in[12];
    const float* ifc_w        = (const float*)d_in[13];
    const float* ifc_b        = (const float*)d_in[14];
    const int*   edge_src     = (const int*)d_in[15];
    const int*   edge_dst     = (const int*)d_in[16];
    const int*   kptr         = (const int*)d_in[17];

    float* ws = (float*)d_ws;
    float* norm_user = ws;
    float* norm_item = norm_user + NU;
    float* user_msg  = norm_item + NI;
    float* item_msg  = user_msg + (long long)NU * DN;
    float* blended   = item_msg + (long long)NI * DN;
    float* hu_t      = blended + (long long)R * E;
    float* hi_t      = hu_t + (long long)R * NU * DN;

    const size_t zero_bytes = (size_t)(NU + NI + NU * DN + NI * DN) * sizeof(float);
    hipMemsetAsync(d_ws, 0, zero_bytes, stream);

    float* ufeat    = (float*)d_out;
    float* ifeat    = ufeat + (long long)NU * DO;
    float* int_dist = ifeat + (long long)NI * DO;

    // Node transform
    {
        dim3 grid((NU + 63) / 64, R, 2);
        nodexf_kernel<<<grid, 256, 0, stream>>>(
            user_h, item_h, node_w_fwd, node_w_rev, kptr, hu_t, hi_t);
    }

    // Pass 1: 4 edges/wave, 16 edges/block; E/16 = 3125 blocks per relation
    {
        dim3 grid(E / 16, R);
        pass1_kernel<<<grid, 256, 0, stream>>>(
            user_h, item_h, user_hsum, item_hsum, review_feat, prototypes,
            eta, edge_src, edge_dst, kptr, blended, norm_user, norm_item);
    }

    // Pass 2b: 64 edges/block
    {
        dim3 grid((E + 63) / 64, R);
        pass2b_kernel<<<grid, 256, 0, stream>>>(
            hu_t, hi_t, review_feat, review_w_fwd, review_w_rev,
            edge_src, edge_dst, kptr, blended, norm_user, norm_item,
            user_msg, item_msg, int_dist);
    }

    // Pass 3
    {
        const long long nthreads = (long long)(NU + NI) * DO;
        const int blocks = (int)((nthreads + 255) / 256);
        pass3_kernel<<<blocks, 256, 0, stream>>>(
            user_msg, item_msg, ufc_w, ufc_b, ifc_w, ifc_b, ufeat, ifeat);
    }
}

// Round 4
// 494.666 us; speedup vs baseline: 1.7746x; 1.7746x over previous
//
#include <hip/hip_runtime.h>
#include <math.h>

// Problem constants (from reference)
constexpr int R  = 5;
constexpr int E  = 50000;   // divisible by 4 (pass1 relies on this)
constexpr int NU = 20000;
constexpr int NI = 20000;
constexpr int NF = 4;
constexpr int DN = 16;
constexpr int DR = 64;
constexpr int DO = 64;
constexpr float TAU = 0.5f;
constexpr float INV_TAU = 2.0f;

// ---------------- Pass 1: 4 edges per wave (16 lanes per edge) ----------------
// lane = e*16 + f*4 + j  (e: edge-in-wave, f: factor, j: sub)
__global__ __launch_bounds__(256) void pass1_kernel(
    const float* __restrict__ user_h,      // (NF,R,NU,DN)
    const float* __restrict__ item_h,      // (NF,R,NI,DN)
    const float* __restrict__ user_hsum,   // (R,NU,NF,DN)
    const float* __restrict__ item_hsum,   // (R,NI,NF,DN)
    const float* __restrict__ review_feat, // (R,E,NF,DR)
    const float* __restrict__ prototypes,  // (NF,DR)
    const float* __restrict__ eta,         // (R,E)
    const int*   __restrict__ edge_src,    // (R,E)
    const int*   __restrict__ edge_dst,    // (R,E)
    const int*   __restrict__ kptr,
    float* __restrict__ blended_out,       // (R*E)
    float* __restrict__ norm_user,         // (NU)
    float* __restrict__ norm_item)         // (NI)
{
    const int lane = threadIdx.x & 63;
    const int w    = threadIdx.x >> 6;
    const int r    = blockIdx.y;
    const int base = (blockIdx.x * 4 + w) * 4;      // edge index within relation
    const int k    = *kptr;

    const int e  = lane >> 4;       // 0..3
    const int le = lane & 15;       // 0..15
    const int f  = le >> 2;         // 0..3
    const int j  = le & 3;          // 0..3

    const int ee = base + e;                        // < E always (E % 4 == 0)
    const long long re = (long long)r * E + ee;

    const int src = edge_src[re];
    const int dst = edge_dst[re];

    // ---- sim_k (l2norm dot over DN=16): quad f==0 only, float4 per lane ----
    float na = 0.f, nb = 0.f, ab = 0.f;
    if (f == 0) {
        const float4 ua = *(const float4*)(user_h + (((long long)k * R + r) * NU + src) * DN + j * 4);
        const float4 ia = *(const float4*)(item_h + (((long long)k * R + r) * NI + dst) * DN + j * 4);
        na = ua.x*ua.x + ua.y*ua.y + ua.z*ua.z + ua.w*ua.w;
        nb = ia.x*ia.x + ia.y*ia.y + ia.z*ia.z + ia.w*ia.w;
        ab = ua.x*ia.x + ua.y*ia.y + ua.z*ia.z + ua.w*ia.w;
    }
    na += __shfl_xor(na, 1, 64); na += __shfl_xor(na, 2, 64);
    nb += __shfl_xor(nb, 1, 64); nb += __shfl_xor(nb, 2, 64);
    ab += __shfl_xor(ab, 1, 64); ab += __shfl_xor(ab, 2, 64);

    // ---- sim_all over hsum rows: lane (f,j) takes floats [f*16 + j*4 ..] ----
    const float4 rs = *(const float4*)(user_hsum + ((long long)r * NU + src) * (NF * DN) + le * 4);
    const float4 cs = *(const float4*)(item_hsum + ((long long)r * NI + dst) * (NF * DN) + le * 4);
    float p = rs.x*cs.x + rs.y*cs.y + rs.z*cs.z + rs.w*cs.w;
    p += __shfl_xor(p, 1, 64); p += __shfl_xor(p, 2, 64);   // sum over j -> sim_all[f]
    float denom_sim = __expf(p * INV_TAU);
    denom_sim += __shfl_xor(denom_sim, 4, 64);
    denom_sim += __shfl_xor(denom_sim, 8, 64);              // sum over f

    // ---- anchors: lane (f,j) reads 4 chunks of rf row (full 64B lines/instr) ----
    const float4* rf4 = (const float4*)review_feat + re * (NF * DR / 4);
    const float4* pr4 = (const float4*)prototypes;
    float q = 0.f;
#pragma unroll
    for (int c = 0; c < 4; ++c) {
        const float4 a = rf4[f * 16 + c * 4 + j];
        const float4 b = pr4[f * 16 + c * 4 + j];
        q += a.x*b.x + a.y*b.y + a.z*b.z + a.w*b.w;
    }
    q += __shfl_xor(q, 1, 64); q += __shfl_xor(q, 2, 64);   // sum over j -> anchor_all[f]
    float ea = __expf(q * INV_TAU);
    float denom_anc = ea;
    denom_anc += __shfl_xor(denom_anc, 4, 64);
    denom_anc += __shfl_xor(denom_anc, 8, 64);              // sum over f
    const float ea_k = __shfl(ea, (lane & 48) | (k << 2), 64);

    if (le == 0) {
        const float sim_k = ab / (fmaxf(sqrtf(na), 1e-12f) * fmaxf(sqrtf(nb), 1e-12f)) * INV_TAU;
        const float exp_anchor = ea_k / denom_anc;
        const float exp_sim    = __expf(sim_k) / denom_sim;
        const float g = 1.0f / (1.0f + __expf(-eta[re]));
        const float blended = g * exp_anchor + (1.0f - g) * exp_sim;
        blended_out[re] = blended;
        atomicAdd(&norm_user[src], blended);
        atomicAdd(&norm_item[dst], blended);
    }
}

// ---------------- Kernel A: dense node transform ----------------
__global__ __launch_bounds__(256) void nodexf_kernel(
    const float* __restrict__ user_h,
    const float* __restrict__ item_h,
    const float* __restrict__ node_w_fwd,   // (R,DN,DN)
    const float* __restrict__ node_w_rev,   // (R,DN,DN)
    const int*   __restrict__ kptr,
    float* __restrict__ hu_t,               // (R,NU,DN)
    float* __restrict__ hi_t)               // (R,NI,DN)
{
    const int r    = blockIdx.y;
    const int side = blockIdx.z;
    const int n0   = blockIdx.x * 64;
    const int k    = *kptr;
    const int N    = side ? NI : NU;
    const float* h    = side ? item_h : user_h;
    const float* wsrc = side ? node_w_rev : node_w_fwd;
    float* out        = side ? hi_t : hu_t;

    __shared__ __align__(16) float lds_h[64 * 16];
    __shared__ float lds_w[16 * 17];

    const int t = threadIdx.x;
    {
        const int o = t >> 4, d = t & 15;
        lds_w[o * 17 + d] = wsrc[((long long)r * DN + o) * DN + d];
    }
    {
        const int row = t >> 2, c = t & 3;
        if (n0 + row < N) {
            const float4 v = *(const float4*)(h + (((long long)k * R + r) * N + n0 + row) * DN + c * 4);
            *(float4*)&lds_h[t * 4] = v;
        }
    }
    __syncthreads();

    const int o = t & 15;
#pragma unroll
    for (int p = 0; p < 4; ++p) {
        const int nl = p * 16 + (t >> 4);
        const int n = n0 + nl;
        if (n < N) {
            float acc = 0.f;
#pragma unroll
            for (int d = 0; d < DN; ++d)
                acc += lds_h[nl * 16 + d] * lds_w[o * 17 + d];
            out[((long long)r * N + n) * DN + o] = acc;
        }
    }
}

// ---------------- Pass 2b: lane-per-edge compute, transposed coalesced atomics ----
// Block: 256 thr = 4 waves; tile = 64 edges. Wave w computes o = w*4..w*4+3 for
// all 64 edges (uniform LDS weight reads). Messages are then transposed through
// LDS so the atomic phase issues wave = 4 edges x 16 contiguous o (4 lines/instr).
__global__ __launch_bounds__(256) void pass2b_kernel(
    const float* __restrict__ hu_t,
    const float* __restrict__ hi_t,
    const float* __restrict__ review_feat,
    const float* __restrict__ review_w_fwd,  // (R,DN,DR)
    const float* __restrict__ review_w_rev,  // (R,DN,DR)
    const int*   __restrict__ edge_src,
    const int*   __restrict__ edge_dst,
    const int*   __restrict__ kptr,
    const float* __restrict__ blended,
    const float* __restrict__ norm_user,
    const float* __restrict__ norm_item,
    float* __restrict__ user_msg,  // (NU,DN)
    float* __restrict__ item_msg,  // (NI,DN)
    float* __restrict__ int_dist)  // (R*E)
{
    constexpr int EPB = 64;
    constexpr int RSTRIDE = 68;        // words; 16B-aligned rows
    constexpr int TSTRIDE = 17;        // transpose-buffer row stride (conflict-free)
    const int r    = blockIdx.y;
    const int e0   = blockIdx.x * EPB;
    const int k    = *kptr;
    const int t    = threadIdx.x;
    const int lane = t & 63;
    const int w    = t >> 6;

    __shared__ __align__(16) float wf[DN * DR];
    __shared__ __align__(16) float wr[DN * DR];
    __shared__ __align__(16) float rf[EPB * RSTRIDE];   // reused as transpose buffer
    __shared__ float wgt_s[EPB];
    __shared__ int   src_s[EPB];
    __shared__ int   dst_s[EPB];

    // stage weights: 1024 floats each, one float4 per thread, coalesced
    {
        const int i = t * 4;
        *(float4*)&wf[i] = *(const float4*)(review_w_fwd + (long long)r * (DN * DR) + i);
        *(float4*)&wr[i] = *(const float4*)(review_w_rev + (long long)r * (DN * DR) + i);
    }
    // stage rf tile: 64 rows x 64 floats; thread t: row t>>2, 64B chunk (t&3)
    {
        const int row = t >> 2;
        const int c0  = (t & 3) * 16;
        const int ee  = e0 + row;
        if (ee < E) {
            const float4* s = (const float4*)(review_feat +
                (((long long)r * E + ee) * NF + k) * DR + c0);
            float4* d = (float4*)&rf[row * RSTRIDE + c0];
            d[0] = s[0]; d[1] = s[1]; d[2] = s[2]; d[3] = s[3];
        }
    }
    // stage per-edge scalars (threads 0..63), write int_dist here
    if (t < EPB) {
        const int ee = e0 + t;
        if (ee < E) {
            const long long re = (long long)r * E + ee;
            const int s  = edge_src[re];
            const int d2 = edge_dst[re];
            src_s[t] = s; dst_s[t] = d2;
            const float wgt = blended[re] * rsqrtf(norm_user[s] * norm_item[d2]);
            wgt_s[t] = wgt;
            int_dist[re] = wgt;
        }
    }
    __syncthreads();

    const int ee = e0 + lane;
    const int ob = w * 4;
    float accf[4] = {0.f, 0.f, 0.f, 0.f};
    float accr[4] = {0.f, 0.f, 0.f, 0.f};

    const float* rfrow = &rf[lane * RSTRIDE];
#pragma unroll 4
    for (int c = 0; c < 16; ++c) {
        const float4 a = *(const float4*)&rfrow[c * 4];          // per-lane b128
#pragma unroll
        for (int jj = 0; jj < 4; ++jj) {
            const float4 bf = *(const float4*)&wf[(ob + jj) * DR + c * 4];  // uniform
            const float4 br = *(const float4*)&wr[(ob + jj) * DR + c * 4];  // uniform
            accf[jj] += a.x*bf.x + a.y*bf.y + a.z*bf.z + a.w*bf.w;
            accr[jj] += a.x*br.x + a.y*br.y + a.z*br.z + a.w*br.w;
        }
    }

    // fold in node transforms + weight, in lane=edge layout (coalesced gathers)
    float msgf[4] = {0.f, 0.f, 0.f, 0.f};
    float msgr[4] = {0.f, 0.f, 0.f, 0.f};
    if (ee < E) {
        const int src = src_s[lane];
        const int dst = dst_s[lane];
        const float wgt = wgt_s[lane];
        const float4 hu = *(const float4*)(hu_t + ((long long)r * NU + src) * DN + ob);
        const float4 hi = *(const float4*)(hi_t + ((long long)r * NI + dst) * DN + ob);
        msgf[0] = (accf[0] + hu.x) * wgt;  msgf[1] = (accf[1] + hu.y) * wgt;
        msgf[2] = (accf[2] + hu.z) * wgt;  msgf[3] = (accf[3] + hu.w) * wgt;
        msgr[0] = (accr[0] + hi.x) * wgt;  msgr[1] = (accr[1] + hi.y) * wgt;
        msgr[2] = (accr[2] + hi.z) * wgt;  msgr[3] = (accr[3] + hi.w) * wgt;
    }

    __syncthreads();                        // rf reads done; safe to reuse
    float* af = rf;                         // [EPB][TSTRIDE]
    float* ar = rf + EPB * TSTRIDE;
#pragma unroll
    for (int jj = 0; jj < 4; ++jj) {
        af[lane * TSTRIDE + ob + jj] = msgf[jj];
        ar[lane * TSTRIDE + ob + jj] = msgr[jj];
    }
    __syncthreads();

    // atomic phase: thread = (edge%16, o); wave = 4 edges x 16 contiguous o
    const int o  = t & 15;
    const int eb = t >> 4;                  // 0..15
#pragma unroll
    for (int p = 0; p < 4; ++p) {
        const int el = eb + p * 16;
        if (e0 + el < E) {
            atomicAdd(&item_msg[(long long)dst_s[el] * DN + o], af[el * TSTRIDE + o]);
            atomicAdd(&user_msg[(long long)src_s[el] * DN + o], ar[el * TSTRIDE + o]);
        }
    }
}

// ---------------- Pass 3: one thread per (node, j) ----------------
__global__ __launch_bounds__(256) void pass3_kernel(
    const float* __restrict__ user_msg,
    const float* __restrict__ item_msg,
    const float* __restrict__ ufc_w,  // (DO,DN)
    const float* __restrict__ ufc_b,  // (DO)
    const float* __restrict__ ifc_w,
    const float* __restrict__ ifc_b,
    float* __restrict__ ufeat,        // (NU,DO)
    float* __restrict__ ifeat)        // (NI,DO)
{
    const long long t = (long long)blockIdx.x * blockDim.x + threadIdx.x;
    const long long nu_total = (long long)NU * DO;
    const long long total = nu_total + (long long)NI * DO;
    if (t >= total) return;
    const bool is_item = (t >= nu_total);
    const long long tt = is_item ? (t - nu_total) : t;
    const int j = (int)(tt & 63);
    const long long n = tt >> 6;

    const float* msg  = (is_item ? item_msg : user_msg) + n * DN;
    const float* wrow = (is_item ? ifc_w : ufc_w) + (long long)j * DN;
    float acc = (is_item ? ifc_b : ufc_b)[j];
#pragma unroll
    for (int d = 0; d < DN; ++d) {
        float x = msg[d];
        x = (x > 0.f) ? x : 0.1f * x;
        acc += x * wrow[d];
    }
    (is_item ? ifeat : ufeat)[tt] = acc;
}

extern "C" void kernel_launch(void* const* d_in, const int* in_sizes, int n_in,
                              void* d_out, int out_size, void* d_ws, size_t ws_size,
                              hipStream_t stream) {
    const float* user_h       = (const float*)d_in[0];
    const float* item_h       = (const float*)d_in[1];
    const float* user_hsum    = (const float*)d_in[2];
    const float* item_hsum    = (const float*)d_in[3];
    const float* review_feat  = (const float*)d_in[4];
    const float* prototypes   = (const float*)d_in[5];
    const float* eta          = (const float*)d_in[6];
    const float* node_w_fwd   = (const float*)d_in[7];
    const float* review_w_fwd = (const float*)d_in[8];
    const float* node_w_rev   = (const float*)d_in[9];
    const float* review_w_rev = (const float*)d_in[10];
    const float* ufc_w        = (const float*)d_in[11];
    const float* ufc_b        = (const float*)d_in[12];
    const float* ifc_w        = (const float*)d_in[13];
    const float* ifc_b        = (const float*)d_in[14];
    const int*   edge_src     = (const int*)d_in[15];
    const int*   edge_dst     = (const int*)d_in[16];
    const int*   kptr         = (const int*)d_in[17];

    float* ws = (float*)d_ws;
    float* norm_user = ws;
    float* norm_item = norm_user + NU;
    float* user_msg  = norm_item + NI;
    float* item_msg  = user_msg + (long long)NU * DN;
    float* blended   = item_msg + (long long)NI * DN;
    float* hu_t      = blended + (long long)R * E;
    float* hi_t      = hu_t + (long long)R * NU * DN;

    const size_t zero_bytes = (size_t)(NU + NI + NU * DN + NI * DN) * sizeof(float);
    hipMemsetAsync(d_ws, 0, zero_bytes, stream);

    float* ufeat    = (float*)d_out;
    float* ifeat    = ufeat + (long long)NU * DO;
    float* int_dist = ifeat + (long long)NI * DO;

    // Node transform
    {
        dim3 grid((NU + 63) / 64, R, 2);
        nodexf_kernel<<<grid, 256, 0, stream>>>(
            user_h, item_h, node_w_fwd, node_w_rev, kptr, hu_t, hi_t);
    }

    // Pass 1: 4 edges/wave, 16 edges/block
    {
        dim3 grid(E / 16, R);
        pass1_kernel<<<grid, 256, 0, stream>>>(
            user_h, item_h, user_hsum, item_hsum, review_feat, prototypes,
            eta, edge_src, edge_dst, kptr, blended, norm_user, norm_item);
    }

    // Pass 2b: 64 edges/block
    {
        dim3 grid((E + 63) / 64, R);
        pass2b_kernel<<<grid, 256, 0, stream>>>(
            hu_t, hi_t, review_feat, review_w_fwd, review_w_rev,
            edge_src, edge_dst, kptr, blended, norm_user, norm_item,
            user_msg, item_msg, int_dist);
    }

    // Pass 3
    {
        const long long nthreads = (long long)(NU + NI) * DO;
        const int blocks = (int)((nthreads + 255) / 256);
        pass3_kernel<<<blocks, 256, 0, stream>>>(
            user_msg, item_msg, ufc_w, ufc_b, ifc_w, ifc_b, ufeat, ifeat);
    }
}